// Round 8
// baseline (90.459 us; speedup 1.0000x reference)
//
#include <hip/hip_runtime.h>

typedef _Float16 f16x8 __attribute__((ext_vector_type(8)));
typedef float f32x4 __attribute__((ext_vector_type(4)));

__device__ __forceinline__ f16x8 splat8(float v) {
  _Float16 h = (_Float16)v;
  return f16x8{h, h, h, h, h, h, h, h};
}

// ------- Kernel 1: x NCHW f32 -> xt NHWC f16 (1024 blks) + weight prep (216 blks) -------
__global__ __launch_bounds__(256) void k_xtprep(const float* __restrict__ x,
                                                const float* __restrict__ wt,
                                                const float* __restrict__ ow,
                                                _Float16* __restrict__ xt,
                                                _Float16* __restrict__ wb,
                                                _Float16* __restrict__ owb) {
  __shared__ float tile[64 * 65];
  int blk = blockIdx.x;
  int t = threadIdx.x;
  if (blk < 1024) {
    int b = blk >> 8;
    int y = (blk >> 1) & 127;
    int w0 = (blk & 1) * 64;
    const float* xp = x + ((size_t)(b * 64) * 128 + y) * 128 + w0;
#pragma unroll
    for (int it = 0; it < 4; ++it) {
      int idx = it * 256 + t;
      int c = idx >> 4, q = idx & 15;
      float4 v = *(const float4*)(xp + (size_t)c * 16384 + q * 4);
      float* tp = &tile[c * 65 + q * 4];
      tp[0] = v.x; tp[1] = v.y; tp[2] = v.z; tp[3] = v.w;
    }
    __syncthreads();
#pragma unroll
    for (int it = 0; it < 2; ++it) {
      int idx = it * 256 + t;
      int w = idx >> 3, c8 = idx & 7;
      f16x8 o;
#pragma unroll
      for (int j = 0; j < 8; ++j) o[j] = (_Float16)tile[(c8 * 8 + j) * 65 + w];
      *(f16x8*)&xt[(((size_t)b * 128 + y) * 128 + w0 + w) * 64 + c8 * 8] = o;
    }
  } else {
    int i = (blk - 1024) * 256 + t;
    if (i < 36864) {
      int k = i >> 12, rem = i & 4095, o = rem >> 6, c = rem & 63;
      wb[i] = (_Float16)wt[(o * 64 + c) * 9 + k];
    } else if (i < 36864 + 18432) {
      int j = i - 36864;
      int k = j >> 11, rem = j & 2047, o = rem >> 6, c = rem & 63;
      float v = (o < 18) ? ow[(o * 64 + c) * 9 + k] : 0.0f;
      owb[j] = (_Float16)v;
    }
  }
}

// ---------------- Kernel 2: fully fused deformable conv (f16) ----------------
// grid 1024 = (2 wtiles of 64px) x (128 h) x (4 b); 256 threads (4 waves)
// Phase A: stage 3x66x64c tile -> LDS; offset conv MFMA -> offL. (2 barriers)
// Phase B: barrier-free. Wave owns 16px x 64o; lane samples its pixel's 16ch
//   (the exact B-fragments); 2-deep cross-tap gather pipeline, full unroll.
__global__ __launch_bounds__(256, 3) void k_fused(
    const _Float16* __restrict__ xt, const _Float16* __restrict__ wb,
    const _Float16* __restrict__ owb, const float* __restrict__ ob,
    const float* __restrict__ bias, float* __restrict__ out) {
  __shared__ _Float16 Xs[3 * 66 * 72];  // 28512 B
  __shared__ float offL[64 * 20];       // 5120 B

  int t = threadIdx.x;
  int wtile = blockIdx.x & 1;
  int h = (blockIdx.x >> 1) & 127;
  int b = blockIdx.x >> 8;
  int w0 = wtile * 64;

  int lane = t & 63, wid = t >> 6;
  int row = lane & 15, quad = lane >> 4;
  const _Float16* xb = xt + (size_t)b * 128 * 128 * 64;

  // ======= Phase A stage: rows h-1..h+1, px w0-1..w0+64, all 64c =======
#pragma unroll
  for (int it = 0; it < 7; ++it) {
    int idx8 = it * 256 + t;  // 1584 chunks of f16x8
    if (idx8 < 1584) {
      int c8 = idx8 & 7;
      int jr = idx8 >> 3;  // 0..197
      int jj = jr % 66;
      int ki = jr / 66;
      int gy = h - 1 + ki;
      int gx = w0 - 1 + jj;
      f16x8 v = {};
      if (((unsigned)gy < 128u) & ((unsigned)gx < 128u))
        v = *(const f16x8*)(xb + ((size_t)gy * 128 + gx) * 64 + c8 * 8);
      *(f16x8*)&Xs[(ki * 66 + jj) * 72 + c8 * 8] = v;
    }
  }
  __syncthreads();

  // ======= Phase A MFMA: M=18pad32, N=64px, K=576 =======
  {
    int woA = (wid >> 1) * 16;
    int wpA = (wid & 1) * 32;
    f32x4 accA[2];
    accA[0] = f32x4{0.f, 0.f, 0.f, 0.f};
    accA[1] = f32x4{0.f, 0.f, 0.f, 0.f};
#pragma unroll
    for (int k = 0; k < 9; ++k) {
      int ki = k / 3, kj = k % 3;
      const _Float16* ap = owb + k * 2048 + (woA + row) * 64 + quad * 8;
      f16x8 afr0 = *(const f16x8*)(ap);
      f16x8 afr1 = *(const f16x8*)(ap + 32);
#pragma unroll
      for (int n = 0; n < 2; ++n) {
        int j = wpA + n * 16 + row + kj;
        const _Float16* lp = &Xs[(ki * 66 + j) * 72 + quad * 8];
        f16x8 b0 = *(const f16x8*)(lp);
        f16x8 b1 = *(const f16x8*)(lp + 32);
        accA[n] = __builtin_amdgcn_mfma_f32_16x16x32_f16(afr0, b0, accA[n], 0, 0, 0);
        accA[n] = __builtin_amdgcn_mfma_f32_16x16x32_f16(afr1, b1, accA[n], 0, 0, 0);
      }
    }
    int qr = quad * 4;
#pragma unroll
    for (int n = 0; n < 2; ++n) {
#pragma unroll
      for (int r = 0; r < 4; ++r) {
        int co = (wid >> 1) * 16 + qr + r;
        if (co < 18)
          offL[(wpA + n * 16 + row) * 20 + co] = accA[n][r] + ob[co];
      }
    }
  }
  __syncthreads();

  // ======= Phase B: barrier-free pipelined sampling + GEMM =======
  int pixw = wid * 16 + row;
  int w = w0 + pixw;

  float dyr[9], dxr[9];
#pragma unroll
  for (int k = 0; k < 9; ++k) {
    dyr[k] = offL[pixw * 20 + 2 * k];
    dxr[k] = offL[pixw * 20 + 2 * k + 1];
  }

  struct Tap {
    f16x8 g[8];
    float wt[4];
  };
  Tap tapA, tapB;

  // issue(k, T): compute weights/addrs for tap k, start the 8 gathers
#define ISSUE_TAP(KK, T)                                                     \
  {                                                                          \
    constexpr int kk = (KK);                                                 \
    float py = dyr[kk] + (float)(h + kk / 3 - 1);                            \
    float pxf = dxr[kk] + (float)(w + kk % 3 - 1);                           \
    float fy = floorf(py), fx = floorf(pxf);                                 \
    float ly = py - fy, lx = pxf - fx;                                       \
    int y0 = (int)fy, x0 = (int)fx;                                          \
    int y1 = y0 + 1, x1 = x0 + 1;                                            \
    bool vy0 = (unsigned)y0 < 128u, vy1 = (unsigned)y1 < 128u;               \
    bool vx0 = (unsigned)x0 < 128u, vx1 = (unsigned)x1 < 128u;               \
    (T).wt[0] = (vy0 && vx0) ? (1.f - ly) * (1.f - lx) : 0.f;                \
    (T).wt[1] = (vy0 && vx1) ? (1.f - ly) * lx : 0.f;                        \
    (T).wt[2] = (vy1 && vx0) ? ly * (1.f - lx) : 0.f;                        \
    (T).wt[3] = (vy1 && vx1) ? ly * lx : 0.f;                                \
    int yc0 = min(max(y0, 0), 127), yc1 = min(max(y1, 0), 127);              \
    int xc0 = min(max(x0, 0), 127), xc1 = min(max(x1, 0), 127);              \
    const _Float16* p = xb + (yc0 * 128 + xc0) * 64 + quad * 8;              \
    int dxo = (xc1 - xc0) * 64;                                              \
    int dyo = (yc1 - yc0) * 8192;                                            \
    (T).g[0] = *(const f16x8*)(p);                                           \
    (T).g[1] = *(const f16x8*)(p + 32);                                      \
    (T).g[2] = *(const f16x8*)(p + dxo);                                     \
    (T).g[3] = *(const f16x8*)(p + dxo + 32);                                \
    (T).g[4] = *(const f16x8*)(p + dyo);                                     \
    (T).g[5] = *(const f16x8*)(p + dyo + 32);                                \
    (T).g[6] = *(const f16x8*)(p + dyo + dxo);                               \
    (T).g[7] = *(const f16x8*)(p + dyo + dxo + 32);                          \
  }

  f32x4 acc[4];
#pragma unroll
  for (int i = 0; i < 4; ++i) acc[i] = f32x4{0.f, 0.f, 0.f, 0.f};

  ISSUE_TAP(0, tapA);
  ISSUE_TAP(1, tapB);

#pragma unroll
  for (int k = 0; k < 9; ++k) {
    Tap& cur = (k & 1) ? tapB : tapA;  // compile-time under full unroll
    // interp: packed f16 math, output IS the two B-fragments
    f16x8 W00 = splat8(cur.wt[0]), W01 = splat8(cur.wt[1]);
    f16x8 W10 = splat8(cur.wt[2]), W11 = splat8(cur.wt[3]);
    f16x8 s0 = W00 * cur.g[0] + W01 * cur.g[2] + W10 * cur.g[4] + W11 * cur.g[6];
    f16x8 s1 = W00 * cur.g[1] + W01 * cur.g[3] + W10 * cur.g[5] + W11 * cur.g[7];
    // refill this slot with tap k+2 (loads overlap the MFMAs below + next iter)
    if (k + 2 < 9) {
      switch (k + 2) {
        case 2: ISSUE_TAP(2, cur); break;
        case 3: ISSUE_TAP(3, cur); break;
        case 4: ISSUE_TAP(4, cur); break;
        case 5: ISSUE_TAP(5, cur); break;
        case 6: ISSUE_TAP(6, cur); break;
        case 7: ISSUE_TAP(7, cur); break;
        case 8: ISSUE_TAP(8, cur); break;
      }
    }
    // MFMA: 4 o-frags x 2 ks; A from L1-hot wb
    const _Float16* wk = wb + k * 4096 + row * 64 + quad * 8;
#pragma unroll
    for (int mi = 0; mi < 4; ++mi) {
      f16x8 af0 = *(const f16x8*)(wk + mi * 1024);
      f16x8 af1 = *(const f16x8*)(wk + mi * 1024 + 32);
      acc[mi] = __builtin_amdgcn_mfma_f32_16x16x32_f16(af0, s0, acc[mi], 0, 0, 0);
      acc[mi] = __builtin_amdgcn_mfma_f32_16x16x32_f16(af1, s1, acc[mi], 0, 0, 0);
    }
  }
#undef ISSUE_TAP

  // epilogue: col=lane&15 (pixel) = row, o = mi*16 + quad*4 + r
  {
    int qr = quad * 4;
#pragma unroll
    for (int mi = 0; mi < 4; ++mi) {
#pragma unroll
      for (int r = 0; r < 4; ++r) {
        int o = mi * 16 + qr + r;
        out[(((size_t)b * 64 + o) * 128 + h) * 128 + w] = acc[mi][r] + bias[o];
      }
    }
  }
}

extern "C" void kernel_launch(void* const* d_in, const int* in_sizes, int n_in,
                              void* d_out, int out_size, void* d_ws,
                              size_t ws_size, hipStream_t stream) {
  const float* x = (const float*)d_in[0];       // (4,64,128,128)
  const float* ow = (const float*)d_in[1];      // (18,64,3,3)
  const float* ob = (const float*)d_in[2];      // (18,)
  const float* wt = (const float*)d_in[3];      // (64,64,3,3)
  const float* bias = (const float*)d_in[4];    // (64,)
  float* out = (float*)d_out;                   // (4,64,128,128)

  char* ws = (char*)d_ws;
  _Float16* xt = (_Float16*)ws;                      // 8,388,608 B
  _Float16* wb = (_Float16*)(ws + 8388608);          // 73,728 B
  _Float16* owb = (_Float16*)(ws + 8388608 + 73728); // 36,864 B

  k_xtprep<<<1240, 256, 0, stream>>>(x, wt, ow, xt, wb, owb);
  k_fused<<<1024, 256, 0, stream>>>(xt, wb, owb, ob, bias, out);
}